// Round 2
// baseline (190.649 us; speedup 1.0000x reference)
//
#include <hip/hip_runtime.h>

#define CCOL 10
#define TPB 256
#define PAIR_BYTES 80                       // 2 rows * 10 f32
#define WAVE_BYTES (64 * PAIR_BYTES)        // 5120 B staged per wave per array
#define CHUNK 1024                          // 64 lanes * 16 B per global_load_lds

typedef const __attribute__((address_space(1))) void* gptr_t;
typedef __attribute__((address_space(3))) void* lptr_t;

__global__ void zero_kernel(float* out) {
    if (threadIdx.x == 0 && blockIdx.x == 0) out[0] = 0.0f;
}

__global__ __launch_bounds__(TPB) void ce_kernel(
    const float* __restrict__ x, const float* __restrict__ tgt,
    const float* __restrict__ exp_c, const float* __restrict__ inv_c,
    const float* __restrict__ log_c, const int* __restrict__ iters_p,
    float* __restrict__ out, int npairs, int full_blocks, float neg_inv_b)
{
    __shared__ float sx[TPB * 2 * CCOL];    // 20 KiB
    __shared__ float st[TPB * 2 * CCOL];    // 20 KiB

    // Coefficients: uniform addresses -> s_load broadcast.
    float ec[9], ic[5], lc[9];
#pragma unroll
    for (int i = 0; i < 9; i++) ec[i] = exp_c[i];
#pragma unroll
    for (int i = 0; i < 5; i++) ic[i] = inv_c[i];
#pragma unroll
    for (int i = 0; i < 9; i++) lc[i] = log_c[i];
    const int niter = iters_p[0];

    const int tid  = threadIdx.x;
    const int lane = tid & 63;
    const int w    = tid >> 6;
    const int pair0 = blockIdx.x * TPB;

    float xr[2 * CCOL], tr[2 * CCOL];
    bool have = false;

    if (blockIdx.x < full_blocks) {
        // ---- staged path: wave w DMAs its own 64 row-pairs into LDS ----
        const char* gx = (const char*)x   + (size_t)pair0 * PAIR_BYTES + w * WAVE_BYTES + lane * 16;
        const char* gt = (const char*)tgt + (size_t)pair0 * PAIR_BYTES + w * WAVE_BYTES + lane * 16;
        char* lx = (char*)sx + w * WAVE_BYTES + lane * 16;
        char* lt = (char*)st + w * WAVE_BYTES + lane * 16;
#pragma unroll
        for (int i = 0; i < 5; i++)
            __builtin_amdgcn_global_load_lds((gptr_t)(gx + i * CHUNK), (lptr_t)(lx + i * CHUNK), 16, 0, 0);
#pragma unroll
        for (int i = 0; i < 5; i++)
            __builtin_amdgcn_global_load_lds((gptr_t)(gt + i * CHUNK), (lptr_t)(lt + i * CHUNK), 16, 0, 0);
        __syncthreads();   // drains vmcnt; block-uniform branch so this is legal

        const float4* xv = (const float4*)(sx + tid * 2 * CCOL);
        const float4* tv = (const float4*)(st + tid * 2 * CCOL);
#pragma unroll
        for (int i = 0; i < 5; i++) {
            float4 v = xv[i];
            xr[4 * i + 0] = v.x; xr[4 * i + 1] = v.y;
            xr[4 * i + 2] = v.z; xr[4 * i + 3] = v.w;
        }
#pragma unroll
        for (int i = 0; i < 5; i++) {
            float4 v = tv[i];
            tr[4 * i + 0] = v.x; tr[4 * i + 1] = v.y;
            tr[4 * i + 2] = v.z; tr[4 * i + 3] = v.w;
        }
        have = true;
    } else {
        // ---- tail block: direct loads, guarded ----
        int p = pair0 + tid;
        if (p < npairs) {
            const float4* xv = (const float4*)(x   + (size_t)p * 2 * CCOL);
            const float4* tv = (const float4*)(tgt + (size_t)p * 2 * CCOL);
#pragma unroll
            for (int i = 0; i < 5; i++) {
                float4 v = xv[i];
                xr[4 * i + 0] = v.x; xr[4 * i + 1] = v.y;
                xr[4 * i + 2] = v.z; xr[4 * i + 3] = v.w;
            }
#pragma unroll
            for (int i = 0; i < 5; i++) {
                float4 v = tv[i];
                tr[4 * i + 0] = v.x; tr[4 * i + 1] = v.y;
                tr[4 * i + 2] = v.z; tr[4 * i + 3] = v.w;
            }
            have = true;
        }
    }

    float local = 0.0f;
    if (have) {
#pragma unroll
        for (int r = 0; r < 2; r++) {
            float e[CCOL];
            float s = 0.0f;
#pragma unroll
            for (int c = 0; c < CCOL; c++) {
                float xx = xr[r * CCOL + c];
                float v = ec[8];
#pragma unroll
                for (int i = 7; i >= 0; i--) v = fmaf(v, xx, ec[i]);
                e[c] = v;
                s += v;
            }
            float inv = ic[4];
#pragma unroll
            for (int i = 3; i >= 0; i--) inv = fmaf(inv, s, ic[i]);
            for (int k = 0; k < niter; k++) inv = inv * (2.0f - s * inv);

#pragma unroll
            for (int c = 0; c < CCOL; c++) {
                float sm = e[c] * inv;
                float v = lc[8];
#pragma unroll
                for (int i = 7; i >= 0; i--) v = fmaf(v, sm, lc[i]);
                local = fmaf(tr[r * CCOL + c], v, local);
            }
        }
    }

    // wave64 shuffle reduce
#pragma unroll
    for (int off = 32; off > 0; off >>= 1)
        local += __shfl_down(local, off, 64);

    __shared__ float wsum[4];
    if (lane == 0) wsum[w] = local;
    __syncthreads();
    if (tid == 0) {
        float b = wsum[0] + wsum[1] + wsum[2] + wsum[3];
        atomicAdd(out, b * neg_inv_b);
    }
}

extern "C" void kernel_launch(void* const* d_in, const int* in_sizes, int n_in,
                              void* d_out, int out_size, void* d_ws, size_t ws_size,
                              hipStream_t stream) {
    const float* x  = (const float*)d_in[0];
    const float* t  = (const float*)d_in[1];
    const float* ec = (const float*)d_in[2];
    const float* ic = (const float*)d_in[3];
    const float* lc = (const float*)d_in[4];
    const int*   it = (const int*)d_in[5];
    float* out = (float*)d_out;

    int b_rows = in_sizes[0] / CCOL;      // 2,000,000
    int npairs = b_rows / 2;              // 1,000,000
    float neg_inv_b = -1.0f / (float)b_rows;

    int full_blocks = npairs / TPB;                    // 3906 staged blocks
    int tail = npairs - full_blocks * TPB;             // 64 leftover pairs
    int blocks = full_blocks + (tail ? 1 : 0);

    zero_kernel<<<1, 64, 0, stream>>>(out);
    ce_kernel<<<blocks, TPB, 0, stream>>>(x, t, ec, ic, lc, it, out,
                                          npairs, full_blocks, neg_inv_b);
}

// Round 3
// 185.206 us; speedup vs baseline: 1.0294x; 1.0294x over previous
//
#include <hip/hip_runtime.h>

#define CCOL 10
#define TPB 256
#define PAIR_BYTES 80                       // 2 rows * 10 f32
#define WAVE_BYTES (64 * PAIR_BYTES)        // 5120 B staged per wave per array
#define CHUNK_LD 1024                       // 64 lanes * 16 B per global_load_lds
#define NBLOCKS 768                         // 3 blocks/CU * 256 CUs (LDS-limited)

typedef const __attribute__((address_space(1))) void* gptr_t;
typedef __attribute__((address_space(3))) void* lptr_t;

__global__ __launch_bounds__(TPB) void ce_kernel(
    const float* __restrict__ x, const float* __restrict__ tgt,
    const float* __restrict__ exp_c, const float* __restrict__ inv_c,
    const float* __restrict__ log_c, const int* __restrict__ iters_p,
    float* __restrict__ partials, int npairs, int full_chunks, int total_chunks)
{
    __shared__ float sx[TPB * 2 * CCOL];    // 20 KiB
    __shared__ float st[TPB * 2 * CCOL];    // 20 KiB

    float ec[9], ic[5], lc[9];
#pragma unroll
    for (int i = 0; i < 9; i++) ec[i] = exp_c[i];
#pragma unroll
    for (int i = 0; i < 5; i++) ic[i] = inv_c[i];
#pragma unroll
    for (int i = 0; i < 9; i++) lc[i] = log_c[i];
    const int niter = iters_p[0];

    const int tid  = threadIdx.x;
    const int lane = tid & 63;
    const int w    = tid >> 6;

    float local = 0.0f;

    for (int c = blockIdx.x; c < total_chunks; c += gridDim.x) {
        const int pair0 = c * TPB;
        float xr[2 * CCOL], tr[2 * CCOL];
        bool have = false;

        if (c < full_chunks) {
            // ---- staged path: wave w DMAs its own 64 row-pairs into LDS ----
            const char* gx = (const char*)x   + (size_t)pair0 * PAIR_BYTES + w * WAVE_BYTES + lane * 16;
            const char* gt = (const char*)tgt + (size_t)pair0 * PAIR_BYTES + w * WAVE_BYTES + lane * 16;
            char* lx = (char*)sx + w * WAVE_BYTES + lane * 16;
            char* lt = (char*)st + w * WAVE_BYTES + lane * 16;
#pragma unroll
            for (int i = 0; i < 5; i++)
                __builtin_amdgcn_global_load_lds((gptr_t)(gx + i * CHUNK_LD), (lptr_t)(lx + i * CHUNK_LD), 16, 0, 0);
#pragma unroll
            for (int i = 0; i < 5; i++)
                __builtin_amdgcn_global_load_lds((gptr_t)(gt + i * CHUNK_LD), (lptr_t)(lt + i * CHUNK_LD), 16, 0, 0);
            __syncthreads();   // block-uniform branch (c uniform); drains vmcnt

            const float4* xv = (const float4*)(sx + tid * 2 * CCOL);
            const float4* tv = (const float4*)(st + tid * 2 * CCOL);
#pragma unroll
            for (int i = 0; i < 5; i++) {
                float4 v = xv[i];
                xr[4 * i + 0] = v.x; xr[4 * i + 1] = v.y;
                xr[4 * i + 2] = v.z; xr[4 * i + 3] = v.w;
            }
#pragma unroll
            for (int i = 0; i < 5; i++) {
                float4 v = tv[i];
                tr[4 * i + 0] = v.x; tr[4 * i + 1] = v.y;
                tr[4 * i + 2] = v.z; tr[4 * i + 3] = v.w;
            }
            __syncthreads();   // all reads done before next iteration overwrites LDS
            have = true;
        } else {
            // ---- tail chunk: direct loads, guarded ----
            int p = pair0 + tid;
            if (p < npairs) {
                const float4* xv = (const float4*)(x   + (size_t)p * 2 * CCOL);
                const float4* tv = (const float4*)(tgt + (size_t)p * 2 * CCOL);
#pragma unroll
                for (int i = 0; i < 5; i++) {
                    float4 v = xv[i];
                    xr[4 * i + 0] = v.x; xr[4 * i + 1] = v.y;
                    xr[4 * i + 2] = v.z; xr[4 * i + 3] = v.w;
                }
#pragma unroll
                for (int i = 0; i < 5; i++) {
                    float4 v = tv[i];
                    tr[4 * i + 0] = v.x; tr[4 * i + 1] = v.y;
                    tr[4 * i + 2] = v.z; tr[4 * i + 3] = v.w;
                }
                have = true;
            }
        }

        if (have) {
#pragma unroll
            for (int r = 0; r < 2; r++) {
                float e[CCOL];
                float s = 0.0f;
#pragma unroll
                for (int cc = 0; cc < CCOL; cc++) {
                    float xx = xr[r * CCOL + cc];
                    float v = ec[8];
#pragma unroll
                    for (int i = 7; i >= 0; i--) v = fmaf(v, xx, ec[i]);
                    e[cc] = v;
                    s += v;
                }
                float inv = ic[4];
#pragma unroll
                for (int i = 3; i >= 0; i--) inv = fmaf(inv, s, ic[i]);
                for (int k = 0; k < niter; k++) inv = inv * (2.0f - s * inv);

#pragma unroll
                for (int cc = 0; cc < CCOL; cc++) {
                    float sm = e[cc] * inv;
                    float v = lc[8];
#pragma unroll
                    for (int i = 7; i >= 0; i--) v = fmaf(v, sm, lc[i]);
                    local = fmaf(tr[r * CCOL + cc], v, local);
                }
            }
        }
    }

    // per-block reduction, once: wave64 shuffle -> LDS -> single workspace write
#pragma unroll
    for (int off = 32; off > 0; off >>= 1)
        local += __shfl_down(local, off, 64);

    __shared__ float wsum[4];
    if (lane == 0) wsum[w] = local;
    __syncthreads();
    if (tid == 0)
        partials[blockIdx.x] = wsum[0] + wsum[1] + wsum[2] + wsum[3];
}

__global__ __launch_bounds__(TPB) void reduce_kernel(
    const float* __restrict__ partials, float* __restrict__ out, float neg_inv_b)
{
    int tid = threadIdx.x;
    float local = partials[tid] + partials[tid + 256] + partials[tid + 512];
#pragma unroll
    for (int off = 32; off > 0; off >>= 1)
        local += __shfl_down(local, off, 64);
    __shared__ float wsum[4];
    if ((tid & 63) == 0) wsum[tid >> 6] = local;
    __syncthreads();
    if (tid == 0)
        out[0] = (wsum[0] + wsum[1] + wsum[2] + wsum[3]) * neg_inv_b;
}

extern "C" void kernel_launch(void* const* d_in, const int* in_sizes, int n_in,
                              void* d_out, int out_size, void* d_ws, size_t ws_size,
                              hipStream_t stream) {
    const float* x  = (const float*)d_in[0];
    const float* t  = (const float*)d_in[1];
    const float* ec = (const float*)d_in[2];
    const float* ic = (const float*)d_in[3];
    const float* lc = (const float*)d_in[4];
    const int*   it = (const int*)d_in[5];
    float* out = (float*)d_out;
    float* partials = (float*)d_ws;        // 768 floats

    int b_rows = in_sizes[0] / CCOL;       // 2,000,000
    int npairs = b_rows / 2;               // 1,000,000
    float neg_inv_b = -1.0f / (float)b_rows;

    int full_chunks  = npairs / TPB;                      // 3906
    int total_chunks = full_chunks + (npairs % TPB ? 1 : 0); // 3907

    ce_kernel<<<NBLOCKS, TPB, 0, stream>>>(x, t, ec, ic, lc, it, partials,
                                           npairs, full_chunks, total_chunks);
    reduce_kernel<<<1, TPB, 0, stream>>>(partials, out, neg_inv_b);
}